// Round 13
// baseline (81.255 us; speedup 1.0000x reference)
//
#include <hip/hip_runtime.h>

typedef __attribute__((ext_vector_type(8))) short    bf16x8;
typedef __attribute__((ext_vector_type(4))) float    f32x4;
typedef __attribute__((ext_vector_type(4))) float    float4_t;
typedef __attribute__((ext_vector_type(4))) unsigned u32x4;

constexpr int NSAMP    = 32768;
constexpr int INSZ     = 255;
constexpr int DIM      = 256;      // IN_SIZE + bias
constexpr int NSPLIT   = 1023;
constexpr int NCOL     = 1024;     // 1023 split cols + W as col 1023
constexpr int BM       = 128;      // samples per block = 2 halves of 64
constexpr int HALF     = 64;
constexpr int NTHREADS = 512;      // 8 waves
constexpr int NMT      = 4;        // M-tiles per wave per half
constexpr int NPASS    = 8;        // col-tile passes per wave

// LDS (exactly 160 KiB, 1 block/CU, grid == #CUs):
//  [0, 32768)      : x tile bf16 [64][256] (current half), byte ^= (row&7)<<4
//  [32768, 163840) : XA_T bf16 [node 0..1023][sample 0..63]
//                    byte = node*128 + ((s*2) ^ sw(node)), sw = ((n&15)<<3)|((n&1)<<2)
//  part[w][64] f32 overlays wave w's OWN level-9 rows (520+64w, 521+64w):
//  written after wave w's walk, read only by the reduction -- race-free.
constexpr int XA_OFF    = 32768;
constexpr int LDS_BYTES = XA_OFF + NCOL * 128;          // 163840
constexpr size_t WS_NEED = (size_t)NCOL * DIM * 2;      // 512 KiB bf16 fragment buffer

extern __shared__ char smem[];

// NOTE (r2/r6/r9/r10 lesson): inline-asm v_cvt_pk_bf16_f32 on MFMA ACCUMULATOR
// outputs produces NaN (missing MFMA->VALU hazard nops). f2bf (compiler code)
// is safe on accumulators; cvt_pk only on load-produced VGPR data (prep_frag).
__device__ __forceinline__ short f2bf(float f) {
  unsigned x = __builtin_bit_cast(unsigned, f);
  x += 0x7fffu + ((x >> 16) & 1u);            // RNE
  return (short)(x >> 16);
}
__device__ __forceinline__ float bfraw(unsigned hw16) {
  return __builtin_bit_cast(float, hw16 << 16);
}
__device__ __forceinline__ unsigned cvt_pk(float lo, float hi) {
  unsigned r;
  asm("v_cvt_pk_bf16_f32 %0, %1, %2" : "=v"(r) : "v"(lo), "v"(hi));
  return r;
}
__device__ __forceinline__ float clamp01(float v) {
  return fminf(fmaxf(v, 0.f), 1.f);
}

__device__ __forceinline__ int xat_sw(int node) {
  return ((node & 15) << 3) | ((node & 1) << 2);
}
__device__ __forceinline__ float xat_read(const char* __restrict__ xat, int t, int lane2) {
  unsigned hw = *(const unsigned short*)(xat + t * 128 + (lane2 ^ xat_sw(t)));
  return bfraw(hw);
}

// ---------------- prep: A (f32) + W row -> bf16 MFMA-fragment layout in d_ws ------------
__global__ void prep_frag(const float* __restrict__ A, const float* __restrict__ W,
                          u32x4* __restrict__ wsf)
{
  int t    = blockIdx.x * 512 + threadIdx.x;      // 0..32767
  int lane = t & 63;
  int ks   = (t >> 6) & 7;
  int ct   = t >> 9;
  int col  = ct * 16 + (lane & 15);
  int k0   = ks * 32 + ((lane >> 4) << 3);
  const float* src = (col < NSPLIT) ? (A + col * DIM + k0) : (W + k0);
  float4_t a0 = *(const float4_t*)src;
  float4_t a1 = *(const float4_t*)(src + 4);
  u32x4 p;
  p[0] = cvt_pk(a0[0], a0[1]);
  p[1] = cvt_pk(a0[2], a0[3]);
  p[2] = cvt_pk(a1[0], a1[1]);
  p[3] = cvt_pk(a1[2], a1[3]);
  wsf[t] = p;
}

// ---------------- B-fragment load (one col-tile, all 8 k-steps) ----------------
template<bool USE_WS>
__device__ __forceinline__ void load_bfr(int ct, bf16x8* dst, int lane,
                                         const u32x4* __restrict__ wsf,
                                         const float* __restrict__ A,
                                         const float* __restrict__ W)
{
  if constexpr (USE_WS) {
    const u32x4* fp = wsf + ct * 512 + lane;
#pragma unroll
    for (int ks = 0; ks < 8; ++ks)
      dst[ks] = __builtin_bit_cast(bf16x8, fp[ks * 64]);
  } else {
    int col = ct * 16 + (lane & 15);
    int k0  = (lane >> 4) << 3;
    const float* ap = (col < NSPLIT) ? (A + col * DIM) : W;
#pragma unroll
    for (int ks = 0; ks < 8; ++ks) {
      float4_t a0 = *(const float4_t*)(ap + ks * 32 + k0);
      float4_t a1 = *(const float4_t*)(ap + ks * 32 + k0 + 4);
      unsigned q0 = ((unsigned)(unsigned short)f2bf(a0[0])) | (((unsigned)(unsigned short)f2bf(a0[1])) << 16);
      unsigned q1 = ((unsigned)(unsigned short)f2bf(a0[2])) | (((unsigned)(unsigned short)f2bf(a0[3])) << 16);
      unsigned q2 = ((unsigned)(unsigned short)f2bf(a1[0])) | (((unsigned)(unsigned short)f2bf(a1[1])) << 16);
      unsigned q3 = ((unsigned)(unsigned short)f2bf(a1[2])) | (((unsigned)(unsigned short)f2bf(a1[3])) << 16);
      u32x4 p = {q0, q1, q2, q3};
      dst[ks] = __builtin_bit_cast(bf16x8, p);
    }
  }
}

// ---------------- x-tile helpers (one 64-sample half) ----------------
__device__ __forceinline__ void xwrite_elem(int g, float v) {
  int row = g / 255;
  int col = g - row * 255;
  *(short*)(smem + (((row << 9) + (col << 1)) ^ ((row & 7) << 4))) = f2bf(v);
}
__device__ __forceinline__ void xwrite_bias(int tid) {
  if (tid < HALF)
    *(short*)(smem + (((tid << 9) + (255 << 1)) ^ ((tid & 7) << 4))) = (short)0x3f80;
}
__device__ __forceinline__ void preload_xf(bf16x8 (&xf)[NMT][8], int lane) {
#pragma unroll
  for (int mt = 0; mt < NMT; ++mt) {
    int row = mt * 16 + (lane & 15);
#pragma unroll
    for (int ks = 0; ks < 8; ++ks) {
      int kk = ks * 32 + ((lane >> 4) << 3);
      xf[mt][ks] = *(const bf16x8*)(smem + (((row << 9) + (kk << 1)) ^ ((row & 7) << 4)));
    }
  }
}

// ---------------- phase 1: 8 passes; wave owns col-tile ct = p*8 + wave ----------------
template<bool USE_WS>
__device__ __forceinline__ void phase1(bf16x8 (&xf)[NMT][8], bf16x8* b0, bf16x8* b1,
                                       int wave, int lane,
                                       const u32x4* __restrict__ wsf,
                                       const float* __restrict__ A,
                                       const float* __restrict__ W, char* xat)
{
#pragma unroll
  for (int p = 0; p < NPASS; ++p) {
    bf16x8* cur = (p & 1) ? b1 : b0;
    bf16x8* nxt = (p & 1) ? b0 : b1;
    if (p < NPASS - 1)
      load_bfr<USE_WS>((p + 1) * 8 + wave, nxt, lane, wsf, A, W);   // prefetch next

    f32x4 acc[NMT];
#pragma unroll
    for (int mt = 0; mt < NMT; ++mt) acc[mt] = f32x4{0.f, 0.f, 0.f, 0.f};
#pragma unroll
    for (int ks = 0; ks < 8; ++ks) {
#pragma unroll
      for (int mt = 0; mt < NMT; ++mt)
        acc[mt] = __builtin_amdgcn_mfma_f32_16x16x32_bf16(xf[mt][ks], cur[ks], acc[mt], 0, 0, 0);
    }
    int node = (p * 8 + wave) * 16 + (lane & 15);
    int sw   = xat_sw(node);
    char* xrow = xat + node * 128;
#pragma unroll
    for (int mt = 0; mt < NMT; ++mt) {
#pragma unroll
      for (int h = 0; h < 2; ++h) {
        int s0 = mt * 16 + ((lane >> 4) << 2) + h * 2;
        unsigned lo = (unsigned short)f2bf(acc[mt][2 * h]);
        unsigned hi = (unsigned short)f2bf(acc[mt][2 * h + 1]);
        *(unsigned*)(xrow + ((s0 * 2) ^ sw)) = lo | (hi << 16);
      }
    }
  }
}

// ---------------- ballot-DFS walk: lane = sample ----------------
// Ballot-prune at D>1; at D==1 (level-9, most numerous) the ballot+branch costs
// more than the unconditional 11-VALU body, so it's branchless.
template<int D>
__device__ __forceinline__ void dfs(int t, float q, float& acc,
                                    const char* __restrict__ xat, int lane2,
                                    const float* __restrict__ Wz)
{
  if constexpr (D > 1) {
    if (__ballot(q > 0.f) == 0ull) return;
  }
  float xa = xat_read(xat, t, lane2);
  float qL = fminf(q, xa);          // child 2t+1 (odd, left, +)
  float qR = fminf(q, -xa);         // child 2t+2 (even, right, -)
  acc += clamp01(qL) * Wz[2 * t + 1] + clamp01(qR) * Wz[2 * t + 2];
  if constexpr (D > 1) {
    dfs<D - 1>(2 * t + 1, qL, acc, xat, lane2, Wz);
    dfs<D - 1>(2 * t + 2, qR, acc, xat, lane2, Wz);
  }
}

__device__ __forceinline__ float walk(const char* __restrict__ xat, int wave, int lane2,
                                      const float* __restrict__ Wz)
{
  int s3 = 7 + wave;                         // this wave's level-3 subtree root
  int a2 = (s3 - 1) >> 1;
  int a1 = (a2 - 1) >> 1;
  float q = 1.f;
  float x0 = xat_read(xat, 0,  lane2); q = fminf(q, (a1 & 1) ? x0 : -x0);
  float x1 = xat_read(xat, a1, lane2); q = fminf(q, (a2 & 1) ? x1 : -x1);
  float x2 = xat_read(xat, a2, lane2); q = fminf(q, (s3 & 1) ? x2 : -x2);
  float acc = 0.f;
  dfs<7>(s3, q, acc, xat, lane2, Wz);
  if (wave == 0)
    dfs<3>(0, 1.f, acc, xat, lane2, Wz);
  return acc;
}

// part[w] overlays wave w's own level-9 rows 520+64w / 521+64w
__device__ __forceinline__ float* part_base(char* xat, int w) {
  return (float*)(xat + (size_t)(520 + 64 * w) * 128);
}

// ---------------- fused main kernel: one persistent block per CU, two halves --------
template<bool USE_WS>
__global__ __launch_bounds__(NTHREADS) __attribute__((amdgpu_waves_per_eu(2, 2)))
void lt_main(const float* __restrict__ X, const float* __restrict__ A,
             const float* __restrict__ W, const float* __restrict__ Bv,
             const u32x4* __restrict__ wsf, float* __restrict__ Out)
{
  const int tid  = threadIdx.x;
  const int lane = tid & 63;
  const int wave = tid >> 6;
  const int m0   = blockIdx.x * BM;
  char* xat = smem + XA_OFF;
  const float* Wz = W + DIM;
  const float bias = Bv[0] + Wz[0];          // b + root weight (z_root = 1)

  // ---- issue h0 pass-0 B fragments early (L2 latency overlaps X staging) ----
  bf16x8 b0[8], b1[8];
  load_bfr<USE_WS>(wave, b0, lane, wsf, A, W);

  // ---- stage h0 x tile directly ----
  {
    const float4_t* Xt = (const float4_t*)(X + (size_t)m0 * INSZ);
#pragma unroll
    for (int i = 0; i < 8; ++i) {
      int idx = tid + i * NTHREADS;
      if (idx < 4080) {                      // 64*255/4
        float4_t v = Xt[idx];
#pragma unroll
        for (int e = 0; e < 4; ++e) xwrite_elem(idx * 4 + e, v[e]);
      }
    }
    xwrite_bias(tid);
  }
  __syncthreads();

  bf16x8 xf[NMT][8];
  preload_xf(xf, lane);
  // no barrier: phase 1 writes only XA_T, x tile untouched (r6 remat lesson)

  phase1<USE_WS>(xf, b0, b1, wave, lane, wsf, A, W, xat);
  __syncthreads();                           // XA_T(h0) ready

  // ---- T14 async-stage: issue h1 X loads + h1 pass-0 fragments; latency hides
  //      under the entire h0 walk ----
  float4_t xr[8];
  {
    const float4_t* Xt1 = (const float4_t*)(X + (size_t)(m0 + HALF) * INSZ);
#pragma unroll
    for (int i = 0; i < 8; ++i) {
      int idx = tid + i * NTHREADS;
      if (idx < 4080) xr[i] = Xt1[idx];
    }
  }
  load_bfr<USE_WS>(wave, b0, lane, wsf, A, W);   // h1 pass-0 tile

  // ---- h0 walk ----
  {
    float acc = walk(xat, wave, lane << 1, Wz);
    part_base(xat, wave)[lane] = acc;        // own-subtree rows: race-free
  }
  __syncthreads();

  // ---- h0 reduce+out (tid<64) CONCURRENT with h1 x-tile LDS write ----
  if (tid < HALF) {
    float sum = 0.f;
#pragma unroll
    for (int w = 0; w < 8; ++w) sum += part_base(xat, w)[tid];
    float xw = xat_read(xat, 1023, tid << 1);
    Out[m0 + tid] = 1.f / (1.f + __expf(-(sum + xw + bias)));
  }
  {
#pragma unroll
    for (int i = 0; i < 8; ++i) {
      int idx = tid + i * NTHREADS;
      if (idx < 4080) {
        float4_t v = xr[i];
#pragma unroll
        for (int e = 0; e < 4; ++e) xwrite_elem(idx * 4 + e, v[e]);
      }
    }
    xwrite_bias(tid);
  }
  __syncthreads();                           // h1 x tile ready; h0 fully retired

  preload_xf(xf, lane);
  phase1<USE_WS>(xf, b0, b1, wave, lane, wsf, A, W, xat);
  __syncthreads();                           // XA_T(h1) ready

  {
    float acc = walk(xat, wave, lane << 1, Wz);
    part_base(xat, wave)[lane] = acc;
  }
  __syncthreads();

  if (tid < HALF) {
    float sum = 0.f;
#pragma unroll
    for (int w = 0; w < 8; ++w) sum += part_base(xat, w)[tid];
    float xw = xat_read(xat, 1023, tid << 1);
    Out[m0 + HALF + tid] = 1.f / (1.f + __expf(-(sum + xw + bias)));
  }
}

extern "C" void kernel_launch(void* const* d_in, const int* in_sizes, int n_in,
                              void* d_out, int out_size, void* d_ws, size_t ws_size,
                              hipStream_t stream) {
  (void)in_sizes; (void)n_in; (void)out_size;
  const float* X  = (const float*)d_in[0];
  const float* A  = (const float*)d_in[1];
  const float* W  = (const float*)d_in[2];
  const float* Bv = (const float*)d_in[3];
  float* Out = (float*)d_out;

  const bool use_ws = (d_ws != nullptr) && (ws_size >= WS_NEED);
  if (use_ws) {
    prep_frag<<<64, 512, 0, stream>>>(A, W, (u32x4*)d_ws);
    hipFuncSetAttribute(reinterpret_cast<const void*>(lt_main<true>),
                        hipFuncAttributeMaxDynamicSharedMemorySize, LDS_BYTES);
    lt_main<true><<<NSAMP / BM, NTHREADS, LDS_BYTES, stream>>>(
        X, A, W, Bv, (const u32x4*)d_ws, Out);
  } else {
    hipFuncSetAttribute(reinterpret_cast<const void*>(lt_main<false>),
                        hipFuncAttributeMaxDynamicSharedMemorySize, LDS_BYTES);
    lt_main<false><<<NSAMP / BM, NTHREADS, LDS_BYTES, stream>>>(
        X, A, W, Bv, nullptr, Out);
  }
}

// Round 14
// 37.436 us; speedup vs baseline: 2.1705x; 2.1705x over previous
//
#include <hip/hip_runtime.h>

typedef __attribute__((ext_vector_type(8))) short    bf16x8;
typedef __attribute__((ext_vector_type(4))) float    f32x4;
typedef __attribute__((ext_vector_type(4))) float    float4_t;
typedef __attribute__((ext_vector_type(4))) unsigned u32x4;

constexpr int NSAMP    = 32768;
constexpr int INSZ     = 255;
constexpr int DIM      = 256;      // IN_SIZE + bias
constexpr int NSPLIT   = 1023;
constexpr int NCOL     = 1024;     // 1023 split cols + W as col 1023
constexpr int BM       = 64;       // samples per block
constexpr int NTHREADS = 512;      // 8 waves
constexpr int NMT      = 4;        // M-tiles per wave
constexpr int NPASS    = 8;        // col-tile passes per wave (64 tiles / 8 waves)

// LDS (exactly 160 KiB, 1 block/CU):
//  [0, 32768)      : x tile bf16 [64][256], byte ^= (row&7)<<4
//                    (reused as part[8][64] f32 AFTER phase 1 completes)
//  [32768, 163840) : XA_T bf16 [node 0..1023][sample 0..63]
//                    byte = node*128 + ((sample*2) ^ sw(node)),
//                    sw(node) = ((node&15)<<3) | ((node&1)<<2)
//                    -> 2 lanes/bank (free) on MFMA-output stores AND walk reads
constexpr int XA_OFF    = 32768;
constexpr int LDS_BYTES = XA_OFF + NCOL * 128;          // 163840
constexpr size_t WS_NEED = (size_t)NCOL * DIM * 2;      // 512 KiB bf16 fragment buffer

extern __shared__ char smem[];

// NOTE (r2/r6/r9/r10 lesson): inline-asm v_cvt_pk_bf16_f32 on MFMA ACCUMULATOR
// outputs produces NaN (missing MFMA->VALU hazard nops). f2bf (compiler code)
// is safe on accumulators; cvt_pk only on load-produced VGPR data (prep_frag).
__device__ __forceinline__ short f2bf(float f) {
  unsigned x = __builtin_bit_cast(unsigned, f);
  x += 0x7fffu + ((x >> 16) & 1u);            // RNE
  return (short)(x >> 16);
}
__device__ __forceinline__ float bfraw(unsigned hw16) {
  return __builtin_bit_cast(float, hw16 << 16);
}
__device__ __forceinline__ unsigned cvt_pk(float lo, float hi) {
  unsigned r;
  asm("v_cvt_pk_bf16_f32 %0, %1, %2" : "=v"(r) : "v"(lo), "v"(hi));
  return r;
}
__device__ __forceinline__ float clamp01(float v) {
  return fminf(fmaxf(v, 0.f), 1.f);
}

__device__ __forceinline__ int xat_sw(int node) {
  return ((node & 15) << 3) | ((node & 1) << 2);
}
// read XA_T[t][lane]: all lanes same node t -> 128B XOR'd span, 2 lanes/bank
__device__ __forceinline__ float xat_read(const char* __restrict__ xat, int t, int lane2) {
  unsigned hw = *(const unsigned short*)(xat + t * 128 + (lane2 ^ xat_sw(t)));
  return bfraw(hw);
}

// ---------------- prep: A (f32) + W row -> bf16 MFMA-fragment layout in d_ws ------------
// u32x4 index = ct*512 + ks*64 + lane
// holds A[col = ct*16 + (lane&15)][k = ks*32 + (lane>>4)*8 .. +8)  (col 1023 -> W[0:256))
__global__ void prep_frag(const float* __restrict__ A, const float* __restrict__ W,
                          u32x4* __restrict__ wsf)
{
  int t    = blockIdx.x * 512 + threadIdx.x;      // 0..32767
  int lane = t & 63;
  int ks   = (t >> 6) & 7;
  int ct   = t >> 9;
  int col  = ct * 16 + (lane & 15);
  int k0   = ks * 32 + ((lane >> 4) << 3);
  const float* src = (col < NSPLIT) ? (A + col * DIM + k0) : (W + k0);
  float4_t a0 = *(const float4_t*)src;
  float4_t a1 = *(const float4_t*)(src + 4);
  u32x4 p;
  p[0] = cvt_pk(a0[0], a0[1]);
  p[1] = cvt_pk(a0[2], a0[3]);
  p[2] = cvt_pk(a1[0], a1[1]);
  p[3] = cvt_pk(a1[2], a1[3]);
  wsf[t] = p;
}

// ---------------- B-fragment load (one col-tile, all 8 k-steps) ----------------
template<bool USE_WS>
__device__ __forceinline__ void load_bfr(int ct, bf16x8* dst, int lane,
                                         const u32x4* __restrict__ wsf,
                                         const float* __restrict__ A,
                                         const float* __restrict__ W)
{
  if constexpr (USE_WS) {
    const u32x4* fp = wsf + ct * 512 + lane;
#pragma unroll
    for (int ks = 0; ks < 8; ++ks)
      dst[ks] = __builtin_bit_cast(bf16x8, fp[ks * 64]);
  } else {
    int col = ct * 16 + (lane & 15);
    int k0  = (lane >> 4) << 3;
    const float* ap = (col < NSPLIT) ? (A + col * DIM) : W;
#pragma unroll
    for (int ks = 0; ks < 8; ++ks) {
      float4_t a0 = *(const float4_t*)(ap + ks * 32 + k0);
      float4_t a1 = *(const float4_t*)(ap + ks * 32 + k0 + 4);
      unsigned q0 = ((unsigned)(unsigned short)f2bf(a0[0])) | (((unsigned)(unsigned short)f2bf(a0[1])) << 16);
      unsigned q1 = ((unsigned)(unsigned short)f2bf(a0[2])) | (((unsigned)(unsigned short)f2bf(a0[3])) << 16);
      unsigned q2 = ((unsigned)(unsigned short)f2bf(a1[0])) | (((unsigned)(unsigned short)f2bf(a1[1])) << 16);
      unsigned q3 = ((unsigned)(unsigned short)f2bf(a1[2])) | (((unsigned)(unsigned short)f2bf(a1[3])) << 16);
      u32x4 p = {q0, q1, q2, q3};
      dst[ks] = __builtin_bit_cast(bf16x8, p);
    }
  }
}

// ---------------- ballot-DFS walk: lane = sample ----------------
// Prune whole dead subtrees at D>1 (r12 showed pruning pays there); at D==1
// (level-9, the most numerous nodes) ballot+branch costs >= the 11-VALU
// unconditional body, so leaves are branchless.
template<int D>
__device__ __forceinline__ void dfs(int t, float q, float& acc,
                                    const char* __restrict__ xat, int lane2,
                                    const float* __restrict__ Wz)
{
  if constexpr (D > 1) {
    if (__ballot(q > 0.f) == 0ull) return;
  }
  float xa = xat_read(xat, t, lane2);
  float qL = fminf(q, xa);          // child 2t+1 (odd, left, +)
  float qR = fminf(q, -xa);         // child 2t+2 (even, right, -)
  acc += clamp01(qL) * Wz[2 * t + 1] + clamp01(qR) * Wz[2 * t + 2];
  if constexpr (D > 1) {
    dfs<D - 1>(2 * t + 1, qL, acc, xat, lane2, Wz);
    dfs<D - 1>(2 * t + 2, qR, acc, xat, lane2, Wz);
  }
}

// ---------------- fused main kernel ----------------
// 1 block/CU (160 KiB LDS) = 8 waves = 2 waves/EU. __launch_bounds__(512, 2):
// the 2nd arg (min waves/EU = 2) sets the allocator budget to 256 registers --
// the r10 live set (xf 128 + b0/b1 128 + acc) otherwise churns through AGPR
// moves under the default budget (every round so far reported <=128 VGPRs).
template<bool USE_WS>
__global__ __launch_bounds__(NTHREADS, 2)
void lt_main(const float* __restrict__ X, const float* __restrict__ A,
             const float* __restrict__ W, const float* __restrict__ Bv,
             const u32x4* __restrict__ wsf, float* __restrict__ Out)
{
  const int tid  = threadIdx.x;
  const int lane = tid & 63;
  const int wave = tid >> 6;
  const int m0   = blockIdx.x * BM;

  // ---- issue pass-0 B fragments early (L2 latency overlaps X staging) ----
  bf16x8 b0[8], b1[8];
  load_bfr<USE_WS>(wave, b0, lane, wsf, A, W);

  // ---- stage x tile: contiguous 64*255 f32 region, float4 loads ----
  {
    const float4_t* Xt = (const float4_t*)(X + (size_t)m0 * INSZ);
#pragma unroll
    for (int i = 0; i < 8; ++i) {
      int idx = tid + i * NTHREADS;
      if (idx < 4080) {                      // 64*255/4
        float4_t v = Xt[idx];
#pragma unroll
        for (int e = 0; e < 4; ++e) {
          int g   = idx * 4 + e;
          int row = g / 255;
          int col = g - row * 255;
          *(short*)(smem + (((row << 9) + (col << 1)) ^ ((row & 7) << 4))) = f2bf(v[e]);
        }
      }
    }
    if (tid < BM)                            // bias column (=1.0)
      *(short*)(smem + (((tid << 9) + (255 << 1)) ^ ((tid & 7) << 4))) = (short)0x3f80;
  }
  __syncthreads();

  // ---- preload x fragments: 4 M-tiles x 8 K-steps (128 VGPR) ----
  bf16x8 xf[NMT][8];
#pragma unroll
  for (int mt = 0; mt < NMT; ++mt) {
    int row = mt * 16 + (lane & 15);
#pragma unroll
    for (int ks = 0; ks < 8; ++ks) {
      int kk = ks * 32 + ((lane >> 4) << 3);
      xf[mt][ks] = *(const bf16x8*)(smem + (((row << 9) + (kk << 1)) ^ ((row & 7) << 4)));
    }
  }
  // no barrier: phase 1 writes only the XA_T region, x tile stays intact

  char* xat = smem + XA_OFF;

  // ---- phase 1: 8 passes; wave owns col-tile ct = p*8 + wave ----
#pragma unroll
  for (int p = 0; p < NPASS; ++p) {
    bf16x8* cur = (p & 1) ? b1 : b0;
    bf16x8* nxt = (p & 1) ? b0 : b1;
    if (p < NPASS - 1)
      load_bfr<USE_WS>((p + 1) * 8 + wave, nxt, lane, wsf, A, W);   // prefetch next

    f32x4 acc[NMT];
#pragma unroll
    for (int mt = 0; mt < NMT; ++mt) acc[mt] = f32x4{0.f, 0.f, 0.f, 0.f};
#pragma unroll
    for (int ks = 0; ks < 8; ++ks) {
#pragma unroll
      for (int mt = 0; mt < NMT; ++mt)
        acc[mt] = __builtin_amdgcn_mfma_f32_16x16x32_bf16(xf[mt][ks], cur[ks], acc[mt], 0, 0, 0);
    }

    // write XA_T[node][sample]: node = ct*16 + (lane&15); 2 samples per u32 store
    // (f2bf-based pack -- see NOTE at f2bf about the cvt_pk-on-accumulator hazard)
    int node = (p * 8 + wave) * 16 + (lane & 15);
    int sw   = xat_sw(node);
    char* xrow = xat + node * 128;
#pragma unroll
    for (int mt = 0; mt < NMT; ++mt) {
#pragma unroll
      for (int h = 0; h < 2; ++h) {
        int s0 = mt * 16 + ((lane >> 4) << 2) + h * 2;
        unsigned lo = (unsigned short)f2bf(acc[mt][2 * h]);
        unsigned hi = (unsigned short)f2bf(acc[mt][2 * h + 1]);
        *(unsigned*)(xrow + ((s0 * 2) ^ sw)) = lo | (hi << 16);
      }
    }
  }
  __syncthreads();

  // ---- phase 2: transposed walk, lane = sample ----
  const float* Wz    = W + DIM;
  const int    lane2 = lane << 1;

  int s3 = 7 + wave;                         // this wave's level-3 subtree root
  int a2 = (s3 - 1) >> 1;                    // level-2 ancestor
  int a1 = (a2 - 1) >> 1;                    // level-1 ancestor
  float q = 1.f;
  {
    float x0 = xat_read(xat, 0,  lane2); q = fminf(q, (a1 & 1) ? x0 : -x0);
    float x1 = xat_read(xat, a1, lane2); q = fminf(q, (a2 & 1) ? x1 : -x1);
    float x2 = xat_read(xat, a2, lane2); q = fminf(q, (s3 & 1) ? x2 : -x2);
  }
  float acc = 0.f;
  dfs<7>(s3, q, acc, xat, lane2, Wz);        // z-nodes 15..2046 (this subtree)
  if (wave == 0)
    dfs<3>(0, 1.f, acc, xat, lane2, Wz);     // z-nodes 1..14

  // ---- cross-wave reduction via x-tile region (dead: phase 1 is complete) ----
  float* part = (float*)smem;
  part[(wave << 6) + lane] = acc;
  __syncthreads();

  if (tid < BM) {
    float sum = 0.f;
#pragma unroll
    for (int w = 0; w < 8; ++w) sum += part[(w << 6) + tid];
    float xw = xat_read(xat, 1023, tid << 1);       // x.Wx from MFMA col 1023
    float v  = sum + xw + Bv[0] + Wz[0];            // + b + root weight (z0 = 1)
    Out[m0 + tid] = 1.f / (1.f + __expf(-v));
  }
}

extern "C" void kernel_launch(void* const* d_in, const int* in_sizes, int n_in,
                              void* d_out, int out_size, void* d_ws, size_t ws_size,
                              hipStream_t stream) {
  (void)in_sizes; (void)n_in; (void)out_size;
  const float* X  = (const float*)d_in[0];
  const float* A  = (const float*)d_in[1];
  const float* W  = (const float*)d_in[2];
  const float* Bv = (const float*)d_in[3];
  float* Out = (float*)d_out;

  const bool use_ws = (d_ws != nullptr) && (ws_size >= WS_NEED);
  if (use_ws) {
    prep_frag<<<64, 512, 0, stream>>>(A, W, (u32x4*)d_ws);
    hipFuncSetAttribute(reinterpret_cast<const void*>(lt_main<true>),
                        hipFuncAttributeMaxDynamicSharedMemorySize, LDS_BYTES);
    lt_main<true><<<NSAMP / BM, NTHREADS, LDS_BYTES, stream>>>(
        X, A, W, Bv, (const u32x4*)d_ws, Out);
  } else {
    hipFuncSetAttribute(reinterpret_cast<const void*>(lt_main<false>),
                        hipFuncAttributeMaxDynamicSharedMemorySize, LDS_BYTES);
    lt_main<false><<<NSAMP / BM, NTHREADS, LDS_BYTES, stream>>>(
        X, A, W, Bv, nullptr, Out);
  }
}